// Round 15
// baseline (4937.301 us; speedup 1.0000x reference)
//
#include <hip/hip_runtime.h>
#include <hip/hip_bf16.h>

typedef unsigned long long ull;

#define THREADS 1024
#define NWAVE 16
#define NSUB 4              // blocks per cloud
#define MAXLQ 160           // max local (32-pt) groups per sub-block
#define COMM_ULLS 32        // 256 B comm stride per cloud

// ---------------- DPP helpers (rounds 5-14 validated) ---------------------
template<int CTRL, int RM>
__device__ __forceinline__ float fmax_dpp(float v) {
    int s = __builtin_amdgcn_update_dpp(__float_as_int(v), __float_as_int(v), CTRL, RM, 0xf, false);
    return fmaxf(v, __int_as_float(s));
}
template<int CTRL, int RM>
__device__ __forceinline__ float fmin_dpp(float v) {
    int s = __builtin_amdgcn_update_dpp(__float_as_int(v), __float_as_int(v), CTRL, RM, 0xf, false);
    return fminf(v, __int_as_float(s));
}
template<int CTRL, int RM>
__device__ __forceinline__ int imin_dpp(int v) {
    int s = __builtin_amdgcn_update_dpp(v, v, CTRL, RM, 0xf, false);
    return (s < v) ? s : v;
}
template<int CTRL, int RM>
__device__ __forceinline__ ull kmax_dpp(ull k) {
    unsigned hi = (unsigned)(k >> 32), lo = (unsigned)k;
    unsigned hi2 = (unsigned)__builtin_amdgcn_update_dpp((int)hi, (int)hi, CTRL, RM, 0xf, false);
    unsigned lo2 = (unsigned)__builtin_amdgcn_update_dpp((int)lo, (int)lo, CTRL, RM, 0xf, false);
    ull k2 = ((ull)hi2 << 32) | lo2;
    return (k2 > k) ? k2 : k;
}
// 32-lane (half-wave) reduces: lane31 = lanes 0-31 total, lane63 = 32-63
__device__ __forceinline__ float half_fmax(float v) {
    v = fmax_dpp<0x111,0xf>(v); v = fmax_dpp<0x112,0xf>(v);
    v = fmax_dpp<0x114,0xf>(v); v = fmax_dpp<0x118,0xf>(v);
    v = fmax_dpp<0x142,0xa>(v);
    return v;
}
__device__ __forceinline__ float half_fmin(float v) {
    v = fmin_dpp<0x111,0xf>(v); v = fmin_dpp<0x112,0xf>(v);
    v = fmin_dpp<0x114,0xf>(v); v = fmin_dpp<0x118,0xf>(v);
    v = fmin_dpp<0x142,0xa>(v);
    return v;
}
__device__ __forceinline__ int half_imin(int v) {
    v = imin_dpp<0x111,0xf>(v); v = imin_dpp<0x112,0xf>(v);
    v = imin_dpp<0x114,0xf>(v); v = imin_dpp<0x118,0xf>(v);
    v = imin_dpp<0x142,0xa>(v);
    return v;
}
__device__ __forceinline__ float wave_fmax(float v) {
    v = half_fmax(v); v = fmax_dpp<0x143,0xc>(v);
    return v;                       // total in lane 63
}
__device__ __forceinline__ float wave_fmin(float v) {
    v = half_fmin(v); v = fmin_dpp<0x143,0xc>(v);
    return v;
}
__device__ __forceinline__ ull wave_kmax(ull k) {
    k = kmax_dpp<0x111,0xf>(k); k = kmax_dpp<0x112,0xf>(k);
    k = kmax_dpp<0x114,0xf>(k); k = kmax_dpp<0x118,0xf>(k);
    k = kmax_dpp<0x142,0xa>(k); k = kmax_dpp<0x143,0xc>(k);
    return k;
}
__device__ __forceinline__ int morton4(int x, int y, int z) {
    int r = 0;
#pragma unroll
    for (int k = 0; k < 4; ++k)
        r |= ((x >> k & 1) << (3 * k)) | ((y >> k & 1) << (3 * k + 1)) | ((z >> k & 1) << (3 * k + 2));
    return r;
}
__device__ __forceinline__ int cellof(float x, float y, float z,
                                      float bx, float by, float bz,
                                      float ivx, float ivy, float ivz) {
    int ix = (int)((x - bx) * ivx); ix = ix < 0 ? 0 : (ix > 15 ? 15 : ix);
    int iy = (int)((y - by) * ivy); iy = iy < 0 ? 0 : (iy > 15 ? 15 : iy);
    int iz = (int)((z - bz) * ivz); iz = iz < 0 ? 0 : (iz > 15 ? 15 : iz);
    return morton4(ix, iy, iz);
}

// ---- preproc: per cloud -- bbox, Morton counting sort -> gx (global),
// per-32pt-group AABB meta -> global, zero comm, idx_out[0]=0. ----
__global__ __launch_bounds__(THREADS)
void fps_pre(const float* __restrict__ C, float4* __restrict__ gxyzo,
             float* __restrict__ meta, ull* __restrict__ comm,
             int n, int m, int G32, int* __restrict__ idx_out)
{
    const int b = blockIdx.x, t = threadIdx.x;
    const int lane = t & 63, wid = t >> 6, sub32 = lane & 31;
    const float* __restrict__ P = C + (size_t)b * n * 3;
    float4* __restrict__ gx = gxyzo + (size_t)b * (G32 * 32);
    float* __restrict__ M = meta + (size_t)b * G32 * 6;

    __shared__ unsigned s_hist[4096];
    __shared__ float s_red[96];
    __shared__ int s_scan[16];

    // P1: bbox
    float mnx = 1e30f, mny = 1e30f, mnz = 1e30f;
    float mxx = -1e30f, mxy = -1e30f, mxz = -1e30f;
    for (int g = t; g < n; g += THREADS) {
        float x = P[3 * g], y = P[3 * g + 1], z = P[3 * g + 2];
        mnx = fminf(mnx, x); mxx = fmaxf(mxx, x);
        mny = fminf(mny, y); mxy = fmaxf(mxy, y);
        mnz = fminf(mnz, z); mxz = fmaxf(mxz, z);
    }
    mnx = wave_fmin(mnx); mny = wave_fmin(mny); mnz = wave_fmin(mnz);
    mxx = wave_fmax(mxx); mxy = wave_fmax(mxy); mxz = wave_fmax(mxz);
    if (lane == 63) {
        s_red[wid * 6 + 0] = mnx; s_red[wid * 6 + 1] = mny; s_red[wid * 6 + 2] = mnz;
        s_red[wid * 6 + 3] = mxx; s_red[wid * 6 + 4] = mxy; s_red[wid * 6 + 5] = mxz;
    }
    __syncthreads();
    if (t == 0) {
        float a0 = 1e30f, a1 = 1e30f, a2 = 1e30f, b0 = -1e30f, b1 = -1e30f, b2 = -1e30f;
        for (int w = 0; w < NWAVE; ++w) {
            a0 = fminf(a0, s_red[w * 6 + 0]); a1 = fminf(a1, s_red[w * 6 + 1]);
            a2 = fminf(a2, s_red[w * 6 + 2]); b0 = fmaxf(b0, s_red[w * 6 + 3]);
            b1 = fmaxf(b1, s_red[w * 6 + 4]); b2 = fmaxf(b2, s_red[w * 6 + 5]);
        }
        s_red[0] = a0; s_red[1] = a1; s_red[2] = a2;
        s_red[3] = 15.9999f / (b0 - a0 + 1e-20f);
        s_red[4] = 15.9999f / (b1 - a1 + 1e-20f);
        s_red[5] = 15.9999f / (b2 - a2 + 1e-20f);
    }
    __syncthreads();
    const float bx = s_red[0], by = s_red[1], bz = s_red[2];
    const float ivx = s_red[3], ivy = s_red[4], ivz = s_red[5];

    // P2: histogram
    for (int i = t; i < 4096; i += THREADS) s_hist[i] = 0;
    __syncthreads();
    for (int g = t; g < n; g += THREADS) {
        float x = P[3 * g], y = P[3 * g + 1], z = P[3 * g + 2];
        atomicAdd(&s_hist[cellof(x, y, z, bx, by, bz, ivx, ivy, ivz)], 1u);
    }
    __syncthreads();

    // P3: exclusive scan
    {
        unsigned c0 = s_hist[4 * t], c1 = s_hist[4 * t + 1];
        unsigned c2 = s_hist[4 * t + 2], c3 = s_hist[4 * t + 3];
        unsigned sum4 = c0 + c1 + c2 + c3;
        unsigned incl = sum4;
        for (int off = 1; off < 64; off <<= 1) {
            unsigned u = (unsigned)__shfl_up((int)incl, off);
            if (lane >= off) incl += u;
        }
        if (lane == 63) s_scan[wid] = (int)incl;
        __syncthreads();
        unsigned woff = 0;
        for (int w = 0; w < wid; ++w) woff += (unsigned)s_scan[w];
        unsigned base = woff + incl - sum4;
        s_hist[4 * t]     = base;
        s_hist[4 * t + 1] = base + c0;
        s_hist[4 * t + 2] = base + c0 + c1;
        s_hist[4 * t + 3] = base + c0 + c1 + c2;
    }
    __syncthreads();

    // P4: scatter (sorted coords + orig idx in .w)
    for (int g = t; g < n; g += THREADS) {
        float x = P[3 * g], y = P[3 * g + 1], z = P[3 * g + 2];
        unsigned pos = atomicAdd(&s_hist[cellof(x, y, z, bx, by, bz, ivx, ivy, ivz)], 1u);
        gx[pos] = make_float4(x, y, z, (float)g);
    }
    __syncthreads();

    // P5: per-32-pt-group AABB -> global meta (one group per wave)
    for (int g = wid; g < G32; g += NWAVE) {
        int cnt = n - g * 32; if (cnt > 32) cnt = 32;
        bool memb = (lane < 32) && (sub32 < cnt);
        float4 w = make_float4(0.f, 0.f, 0.f, 0.f);
        if (memb) w = gx[g * 32 + sub32];
        float xn = memb ? w.x : 1e30f, xxv = memb ? w.x : -1e30f;
        float yn = memb ? w.y : 1e30f, yxv = memb ? w.y : -1e30f;
        float zn = memb ? w.z : 1e30f, zxv = memb ? w.z : -1e30f;
        xn = __shfl(half_fmin(xn), 31); xxv = __shfl(half_fmax(xxv), 31);
        yn = __shfl(half_fmin(yn), 31); yxv = __shfl(half_fmax(yxv), 31);
        zn = __shfl(half_fmin(zn), 31); zxv = __shfl(half_fmax(zxv), 31);
        if (lane == 0) {
            M[0 * G32 + g] = (xn + xxv) * 0.5f;
            M[1 * G32 + g] = (yn + yxv) * 0.5f;
            M[2 * G32 + g] = (zn + zxv) * 0.5f;
            M[3 * G32 + g] = (xxv - xn) * 0.5f + 1e-7f;
            M[4 * G32 + g] = (yxv - yn) * 0.5f + 1e-7f;
            M[5 * G32 + g] = (zxv - zn) * 0.5f + 1e-7f;
        }
    }
    if (t == 0) idx_out[(size_t)b * m] = 0;
    for (int i = t; i < COMM_ULLS; i += THREADS) comm[(size_t)b * COMM_ULLS + i] = 0;
}

// LDS byte offsets for fps_multi
#define OFS_PTS  0                        // MAXLQ*32*16 = 81920
#define OFS_DIST 81920                    // MAXLQ*32*4 = 20480
#define OFS_CX   102400                   // MAXLQ*4 each
#define OFS_CY   103040
#define OFS_CZ   103680
#define OFS_EX   104320
#define OFS_EY   104960
#define OFS_EZ   105600
#define OFS_GMX  106240
#define OFS_GKEY 106880                   // 256 * 8 = 2048
#define OFS_LIST 108928                   // MAXLQ * 2
#define OFS_MISC 109248                   // ctr / bk
#define SMEM_TOTAL 109568

// Phase C on LDS-resident coords: 2 local groups per wave-pass. Branch-free
// extraction: gm = half-max(nd); mv = half-imin(nd==gm ? (orig<<6)|lane : INF)
// -> exact max-dist / min-ORIG (np.argmax first-occurrence) + winner lane
// for the sorted position. Key = (distbits<<30)|((0x7fff-orig)<<15)|pos.
__device__ __forceinline__ void phaseC_lds(
    const float4* __restrict__ s_pts, float* __restrict__ s_dist,
    ull* __restrict__ s_gkey, float* __restrict__ s_gmx,
    const unsigned short* __restrict__ lst, int U, int base_g,
    int lane, int half, int sub32, int wid,
    float lx, float ly, float lz)
{
    const int nt = (U + 1) >> 1;
    for (int j = wid; j < nt; j += NWAVE) {
        int e = 2 * j + half;
        bool a = (e < U);
        int g = a ? (int)lst[e] : 0;
        int o = g * 32 + sub32;
        float4 w = s_pts[o];
        float dc = a ? s_dist[o] : -1.0f;
        float dx = __fsub_rn(w.x, lx);
        float dy = __fsub_rn(w.y, ly);
        float dz = __fsub_rn(w.z, lz);
        float d  = __fadd_rn(__fadd_rn(__fmul_rn(dx, dx), __fmul_rn(dy, dy)),
                             __fmul_rn(dz, dz));
        float nd = fminf(dc, d);
        if (a) s_dist[o] = nd;
        float gm = __shfl(half_fmax(nd), lane | 31);
        int pi = (nd == gm) ? (((int)w.w << 6) | sub32) : 0x7FFFFFFF;
        int mv = __shfl(half_imin(pi), lane | 31);
        if (a && sub32 == 31) {
            int worig = mv >> 6;
            int fl = mv & 63;
            int pos = (base_g + g) * 32 + fl;
            s_gkey[g] = ((ull)__float_as_uint(gm) << 30)
                      | ((ull)(unsigned)(0x7fff - worig) << 15)
                      | (ull)(unsigned)pos;
            s_gmx[g] = gm;
        }
    }
}

// Multi-block exact lazy-prune FPS: NSUB blocks per cloud, each owning a
// contiguous range of 32-pt groups with coords+dist+meta in LDS. Per round:
// spin(arrive>=NSUB*r, acquire) -> read NSUB keys (parity dbuf) -> max =
// global winner (exact: key orders by dist then min-orig; orig unique) ->
// A prune owned groups -> C update -> D local key max -> publish key +
// release-add arrive. Max skew 1 round -> parity double-buffer is safe.
__global__ __launch_bounds__(THREADS)
void fps_multi(const float* __restrict__ C, const float4* __restrict__ gx_all,
               const float* __restrict__ meta, ull* __restrict__ comm,
               int n, int m, int G32, int Gq, int batch,
               int* __restrict__ idx_out)
{
    const int cloud = blockIdx.x % batch;
    const int sub   = blockIdx.x / batch;     // 0..NSUB-1
    const int t = threadIdx.x;
    const int lane = t & 63;
    const int wid  = t >> 6;
    const int half = lane >> 5;
    const int sub32 = lane & 31;

    const int base_g = sub * Gq;
    int ng = G32 - base_g; if (ng > Gq) ng = Gq; if (ng < 0) ng = 0;

    const float* __restrict__ P = C + (size_t)cloud * n * 3;
    const float4* __restrict__ gx = gx_all + (size_t)cloud * (G32 * 32);
    const float* __restrict__ M = meta + (size_t)cloud * G32 * 6;
    ull* __restrict__ pkb = comm + (size_t)cloud * COMM_ULLS;   // [2][NSUB]
    int* __restrict__ arrive = (int*)(pkb + 2 * NSUB);

    extern __shared__ char smem[];
    float4* s_pts  = (float4*)(smem + OFS_PTS);
    float*  s_dist = (float*)(smem + OFS_DIST);
    float*  s_cx   = (float*)(smem + OFS_CX);
    float*  s_cy   = (float*)(smem + OFS_CY);
    float*  s_cz   = (float*)(smem + OFS_CZ);
    float*  s_ex   = (float*)(smem + OFS_EX);
    float*  s_ey   = (float*)(smem + OFS_EY);
    float*  s_ez   = (float*)(smem + OFS_EZ);
    float*  s_gmx  = (float*)(smem + OFS_GMX);
    ull*    s_gkey = (ull*)(smem + OFS_GKEY);
    unsigned short* s_list = (unsigned short*)(smem + OFS_LIST);
    int*      s_ctr  = (int*)(smem + OFS_MISC);
    unsigned* s_bklo = (unsigned*)(smem + OFS_MISC + 8);
    unsigned* s_bkhi = (unsigned*)(smem + OFS_MISC + 12);

    // init: owned coords + dist + meta into LDS
    for (int i = t; i < ng * 32; i += THREADS) {
        s_pts[i] = gx[base_g * 32 + i];
        s_dist[i] = (base_g * 32 + i < n) ? 1e10f : -1.0f;
    }
    for (int l = t; l < ng; l += THREADS) {
        int g = base_g + l;
        s_cx[l] = M[0 * G32 + g]; s_cy[l] = M[1 * G32 + g]; s_cz[l] = M[2 * G32 + g];
        s_ex[l] = M[3 * G32 + g]; s_ey[l] = M[4 * G32 + g]; s_ez[l] = M[5 * G32 + g];
        s_list[l] = (unsigned short)l;
    }
    for (int i = t; i < 256; i += THREADS) s_gkey[i] = 0;
    if (t == 0) *s_ctr = 0;
    __syncthreads();

    // prologue: apply center 0 to ALL owned groups, publish round-0 partial
    float lx = P[0], ly = P[1], lz = P[2];
    phaseC_lds(s_pts, s_dist, s_gkey, s_gmx, s_list, ng, base_g,
               lane, half, sub32, wid, lx, ly, lz);
    __syncthreads();
    if (wid == 0) {
        ull k = s_gkey[lane];
        ull v = s_gkey[lane + 64];  if (v > k) k = v;
        v = s_gkey[lane + 128];     if (v > k) k = v;
        v = s_gkey[lane + 192];     if (v > k) k = v;
        k = wave_kmax(k);
        unsigned klo = (unsigned)__builtin_amdgcn_readlane((int)(unsigned)k, 63);
        unsigned khi = (unsigned)__builtin_amdgcn_readlane((int)(k >> 32), 63);
        if (lane == 0) {
            ull bk = ((ull)khi << 32) | klo;
            __hip_atomic_store(&pkb[0 * NSUB + sub], bk, __ATOMIC_RELAXED, __HIP_MEMORY_SCOPE_AGENT);
            __hip_atomic_fetch_add(arrive, 1, __ATOMIC_RELEASE, __HIP_MEMORY_SCOPE_AGENT);
        }
    }

    const size_t iobase = (size_t)cloud * m;
    for (int r = 1; r < m; ++r) {
        // spin + combine (wave 0)
        if (wid == 0) {
            ull kv = 0;
            if (lane < NSUB) {
                int target = NSUB * r;
                int guard = 0;
                while (__hip_atomic_load(arrive, __ATOMIC_ACQUIRE, __HIP_MEMORY_SCOPE_AGENT) < target) {
                    __builtin_amdgcn_s_sleep(2);
                    if (++guard > (1 << 27)) break;
                }
                kv = __hip_atomic_load(&pkb[((r - 1) & 1) * NSUB + lane],
                                       __ATOMIC_RELAXED, __HIP_MEMORY_SCOPE_AGENT);
            }
            ull o1 = __shfl_xor(kv, 1); if (o1 > kv) kv = o1;
            o1 = __shfl_xor(kv, 2);     if (o1 > kv) kv = o1;
            if (lane == 0) { *s_bklo = (unsigned)kv; *s_bkhi = (unsigned)(kv >> 32); }
        }
        __syncthreads();                              // B1
        ull bk = ((ull)(*s_bkhi) << 32) | (*s_bklo);
        int pos  = (int)(bk & 0x7fffu);
        int orig = 0x7fff - (int)((bk >> 15) & 0x7fffu);
        if (sub == 0 && t == 0) idx_out[iobase + r] = orig;
        if (r == m - 1) break;
        int sp = __builtin_amdgcn_readfirstlane(pos);
        float4 wn = gx[sp];                           // immutable -> race-free
        lx = wn.x; ly = wn.y; lz = wn.z;

        // A: AABB prune owned groups, ballot-compact (invariant: a skipped
        // group has lb2 <= min d(p,c)^2 and lb2 >= gmax >= dist_p -> no change)
        bool upd = false;
        if (t < ng) {
            float gmax = s_gmx[t];
            float ax = fmaxf(fabsf(lx - s_cx[t]) - s_ex[t], 0.0f);
            float ay = fmaxf(fabsf(ly - s_cy[t]) - s_ey[t], 0.0f);
            float az = fmaxf(fabsf(lz - s_cz[t]) - s_ez[t], 0.0f);
            float lb2 = ax * ax + ay * ay + az * az;
            upd = !(lb2 * 0.9999f - 1e-6f >= gmax);
        }
        {
            ull mask = __ballot(upd);
            if (mask) {
                int cnt = __popcll(mask);
                int base = 0;
                if (lane == 0) base = atomicAdd(s_ctr, cnt);
                base = __shfl(base, 0);
                if (upd) {
                    int pw = (int)__popcll(mask & ((1ULL << lane) - 1ULL));
                    s_list[base + pw] = (unsigned short)t;
                }
            }
        }
        __syncthreads();                              // B2
        const int U = *s_ctr;

        // C: update listed groups (LDS coords)
        phaseC_lds(s_pts, s_dist, s_gkey, s_gmx, s_list, U, base_g,
                   lane, half, sub32, wid, lx, ly, lz);
        __syncthreads();                              // B3
        if (t == 0) *s_ctr = 0;

        // D + publish (wave 0; other waves run ahead to next B1)
        if (wid == 0) {
            ull k = s_gkey[lane];
            ull v = s_gkey[lane + 64];  if (v > k) k = v;
            v = s_gkey[lane + 128];     if (v > k) k = v;
            v = s_gkey[lane + 192];     if (v > k) k = v;
            k = wave_kmax(k);
            unsigned klo = (unsigned)__builtin_amdgcn_readlane((int)(unsigned)k, 63);
            unsigned khi = (unsigned)__builtin_amdgcn_readlane((int)(k >> 32), 63);
            if (lane == 0) {
                ull pk = ((ull)khi << 32) | klo;
                __hip_atomic_store(&pkb[(r & 1) * NSUB + sub], pk, __ATOMIC_RELAXED, __HIP_MEMORY_SCOPE_AGENT);
                __hip_atomic_fetch_add(arrive, 1, __ATOMIC_RELEASE, __HIP_MEMORY_SCOPE_AGENT);
            }
        }
    }
}

// Fallback for shapes outside the grouped path: exact brute force.
__global__ __launch_bounds__(1024)
void fps_brute(const float* __restrict__ C, float* __restrict__ gdist,
               int n, int m, int* __restrict__ idx_out) {
    const int b = blockIdx.x, t = threadIdx.x;
    const int lane = t & 63, wid = t >> 6;
    const float* __restrict__ P = C + (size_t)b * n * 3;
    float* __restrict__ dist = gdist + (size_t)b * n;
    __shared__ ull sp[2][16];
    for (int g = t; g < n; g += 1024) dist[g] = 1e10f;
    if (t == 0) idx_out[(size_t)b * m] = 0;
    float lx = P[0], ly = P[1], lz = P[2];
    __syncthreads();
    for (int it = 1; it < m; ++it) {
        int par = it & 1;
        ull k = 0;
        for (int g = t; g < n; g += 1024) {
            float dx = __fsub_rn(P[3 * g], lx);
            float dy = __fsub_rn(P[3 * g + 1], ly);
            float dz = __fsub_rn(P[3 * g + 2], lz);
            float d = __fadd_rn(__fadd_rn(__fmul_rn(dx, dx), __fmul_rn(dy, dy)),
                                __fmul_rn(dz, dz));
            float nd = fminf(dist[g], d);
            dist[g] = nd;
            ull kk = ((ull)__float_as_uint(nd) << 32) | (unsigned)(~g);
            if (kk > k) k = kk;
        }
        for (int off = 1; off < 64; off <<= 1) {
            ull ok = __shfl_xor(k, off);
            if (ok > k) k = ok;
        }
        if (lane == 0) sp[par][wid] = k;
        __syncthreads();
        ull kmaxv = sp[par][0];
        for (int w = 1; w < 16; ++w) { ull v = sp[par][w]; if (v > kmaxv) kmaxv = v; }
        int sbi = (int)~(unsigned)kmaxv;
        if (t == 0) idx_out[(size_t)b * m + it] = sbi;
        const float* wp = P + 3 * (size_t)(unsigned)sbi;
        lx = wp[0]; ly = wp[1]; lz = wp[2];
    }
}

__global__ void gather_kernel(const float* __restrict__ C,
                              const float* __restrict__ F,
                              const int* __restrict__ idx,
                              float* __restrict__ outC,
                              float* __restrict__ outF,
                              int n_pts, int m, int c) {
    int pair = blockIdx.x;            // b*m + s
    int b = pair / m;
    int src = idx[pair];
    size_t srcbase = (size_t)b * n_pts + src;
    const float* sF = F + srcbase * (size_t)c;
    float* dF = outF + (size_t)pair * c;
    for (int i = threadIdx.x; i < c; i += blockDim.x) dF[i] = sF[i];
    if (threadIdx.x < 3)
        outC[(size_t)pair * 3 + threadIdx.x] = C[srcbase * 3 + threadIdx.x];
}

extern "C" void kernel_launch(void* const* d_in, const int* in_sizes, int n_in,
                              void* d_out, int out_size, void* d_ws, size_t ws_size,
                              hipStream_t stream) {
    const float* C = (const float*)d_in[0];
    const float* F = (const float*)d_in[1];

    int n_total = in_sizes[0] / 3;
    int c       = in_sizes[1] / n_total;
    int bm      = out_size / (3 + c);

    int batch = 8;
    if (bm % 2000 == 0) {
        int bb = bm / 2000;
        if (bb > 0 && n_total % bb == 0 && n_total / bb >= 2000) batch = bb;
    }
    int n_pts = n_total / batch;
    int m     = (n_pts < 2000) ? n_pts : 2000;

    int* idxbuf = (int*)d_ws;
    float* outC = (float*)d_out;
    float* outF = outC + (size_t)batch * m * 3;

    int G32 = (n_pts + 31) >> 5;
    int Gq  = (G32 + NSUB - 1) / NSUB;
    int GP  = G32 * 32;
    size_t idxbytes  = (((size_t)batch * m * 4) + 255) & ~(size_t)255;
    size_t commbytes = (size_t)batch * 256;
    size_t gxbytes   = (size_t)batch * GP * 16;
    size_t metabytes = (((size_t)batch * G32 * 24) + 255) & ~(size_t)255;
    size_t scr = commbytes + gxbytes + metabytes;
    char* sbase;
    if (ws_size >= idxbytes + scr)
        sbase = (char*)d_ws + idxbytes;
    else
        sbase = (char*)d_out + ((((size_t)out_size * 4) - scr) & ~(size_t)255);
    ull*    comm = (ull*)sbase;
    float4* gxb  = (float4*)(sbase + commbytes);
    float*  meta = (float*)(sbase + commbytes + gxbytes);

    if (Gq <= MAXLQ && n_pts <= 32767) {
        fps_pre<<<batch, THREADS, 0, stream>>>(C, gxb, meta, comm,
                                               n_pts, m, G32, idxbuf);
        hipFuncSetAttribute((const void*)fps_multi,
                            hipFuncAttributeMaxDynamicSharedMemorySize, SMEM_TOTAL);
        fps_multi<<<batch * NSUB, THREADS, SMEM_TOTAL, stream>>>(
            C, gxb, meta, comm, n_pts, m, G32, Gq, batch, idxbuf);
    } else {
        fps_brute<<<batch, 1024, 0, stream>>>(C, (float*)(sbase + commbytes),
                                              n_pts, m, idxbuf);
    }

    gather_kernel<<<batch * m, 128, 0, stream>>>(C, F, idxbuf, outC, outF,
                                                 n_pts, m, c);
}

// Round 16
// 3180.664 us; speedup vs baseline: 1.5523x; 1.5523x over previous
//
#include <hip/hip_runtime.h>
#include <hip/hip_bf16.h>

typedef unsigned long long ull;

#define THREADS 1024
#define NWAVE 16

// ---------------- DPP helpers (rounds 5-15 validated) ---------------------
template<int CTRL, int RM>
__device__ __forceinline__ float fmax_dpp(float v) {
    int s = __builtin_amdgcn_update_dpp(__float_as_int(v), __float_as_int(v), CTRL, RM, 0xf, false);
    return fmaxf(v, __int_as_float(s));
}
template<int CTRL, int RM>
__device__ __forceinline__ float fmin_dpp(float v) {
    int s = __builtin_amdgcn_update_dpp(__float_as_int(v), __float_as_int(v), CTRL, RM, 0xf, false);
    return fminf(v, __int_as_float(s));
}
template<int CTRL, int RM>
__device__ __forceinline__ int imin_dpp(int v) {
    int s = __builtin_amdgcn_update_dpp(v, v, CTRL, RM, 0xf, false);
    return (s < v) ? s : v;
}
template<int CTRL, int RM>
__device__ __forceinline__ ull kmax_dpp(ull k) {
    unsigned hi = (unsigned)(k >> 32), lo = (unsigned)k;
    unsigned hi2 = (unsigned)__builtin_amdgcn_update_dpp((int)hi, (int)hi, CTRL, RM, 0xf, false);
    unsigned lo2 = (unsigned)__builtin_amdgcn_update_dpp((int)lo, (int)lo, CTRL, RM, 0xf, false);
    ull k2 = ((ull)hi2 << 32) | lo2;
    return (k2 > k) ? k2 : k;
}
__device__ __forceinline__ float wave_fmax(float v) {
    v = fmax_dpp<0x111,0xf>(v); v = fmax_dpp<0x112,0xf>(v);
    v = fmax_dpp<0x114,0xf>(v); v = fmax_dpp<0x118,0xf>(v);
    v = fmax_dpp<0x142,0xa>(v); v = fmax_dpp<0x143,0xc>(v);
    return v;                       // total in lane 63
}
__device__ __forceinline__ float wave_fmin(float v) {
    v = fmin_dpp<0x111,0xf>(v); v = fmin_dpp<0x112,0xf>(v);
    v = fmin_dpp<0x114,0xf>(v); v = fmin_dpp<0x118,0xf>(v);
    v = fmin_dpp<0x142,0xa>(v); v = fmin_dpp<0x143,0xc>(v);
    return v;
}
// 32-lane (half-wave) reduces: lane31 = lanes 0-31 total, lane63 = 32-63
__device__ __forceinline__ float half_fmax(float v) {
    v = fmax_dpp<0x111,0xf>(v); v = fmax_dpp<0x112,0xf>(v);
    v = fmax_dpp<0x114,0xf>(v); v = fmax_dpp<0x118,0xf>(v);
    v = fmax_dpp<0x142,0xa>(v);
    return v;
}
__device__ __forceinline__ float half_fmin(float v) {
    v = fmin_dpp<0x111,0xf>(v); v = fmin_dpp<0x112,0xf>(v);
    v = fmin_dpp<0x114,0xf>(v); v = fmin_dpp<0x118,0xf>(v);
    v = fmin_dpp<0x142,0xa>(v);
    return v;
}
__device__ __forceinline__ int half_imin(int v) {
    v = imin_dpp<0x111,0xf>(v); v = imin_dpp<0x112,0xf>(v);
    v = imin_dpp<0x114,0xf>(v); v = imin_dpp<0x118,0xf>(v);
    v = imin_dpp<0x142,0xa>(v);
    return v;
}
__device__ __forceinline__ ull wave_kmax(ull k) {
    k = kmax_dpp<0x111,0xf>(k); k = kmax_dpp<0x112,0xf>(k);
    k = kmax_dpp<0x114,0xf>(k); k = kmax_dpp<0x118,0xf>(k);
    k = kmax_dpp<0x142,0xa>(k); k = kmax_dpp<0x143,0xc>(k);
    return k;
}
__device__ __forceinline__ int morton4(int x, int y, int z) {
    int r = 0;
#pragma unroll
    for (int k = 0; k < 4; ++k)
        r |= ((x >> k & 1) << (3 * k)) | ((y >> k & 1) << (3 * k + 1)) | ((z >> k & 1) << (3 * k + 2));
    return r;
}
__device__ __forceinline__ int cellof(float x, float y, float z,
                                      float bx, float by, float bz,
                                      float ivx, float ivy, float ivz) {
    int ix = (int)((x - bx) * ivx); ix = ix < 0 ? 0 : (ix > 15 ? 15 : ix);
    int iy = (int)((y - by) * ivy); iy = iy < 0 ? 0 : (iy > 15 ? 15 : iy);
    int iz = (int)((z - bz) * ivz); iz = iz < 0 ? 0 : (iz > 15 ? 15 : iz);
    return morton4(ix, iy, iz);
}

// LDS fixed-region byte offsets (dist/hist region follows at FIXED_BYTES)
#define OFS_GKEY 0          // 1024 * ull
#define OFS_GMAX 8192       // 1024 * f32
#define OFS_CX   12288      // AABB mid x
#define OFS_CY   16384
#define OFS_CZ   20480
#define OFS_EX   24576      // AABB half-extent x
#define OFS_EY   28672
#define OFS_EZ   32768
#define OFS_LIST 36864      // 1024 * u16
#define OFS_PART 38912      // 32 * ull
#define OFS_MISC 39168      // 32 * int ([0]=count, [8..23]=P3 scan)
#define OFS_RED  39296      // 96 * f32
#define FIXED_BYTES 39680

// Exact grouped lazy-prune FPS, 32-pt groups, AABB bounds (r11 champion)
// + r16 no-op-group skip in Phase C.
// Skipped-group invariant: computed lower bound lb2 <= min_p d(p,c)^2 (with
// conservative 0.9999/-1e-6 slack); prune iff lb2 >= gmax >= dist_p -> no
// dist would change. Exactness never depends on bound quality.
// Keys: (distbits<<15) | (0x7fff-orig): max key = max dist, ties to the
// SMALLEST original index (np.argmax first-occurrence).
__global__ __launch_bounds__(THREADS)
void fps_grouped(const float* __restrict__ C, float4* __restrict__ gxyzo,
                 int n, int m, int G32, int* __restrict__ idx_out) {
    const int b = blockIdx.x;
    const int t = threadIdx.x;
    const int lane = t & 63;
    const int wid  = t >> 6;
    const int half = lane >> 5;
    const int sub  = lane & 31;
    const int GP = G32 * 32;
    const float* __restrict__ P = C + (size_t)b * n * 3;
    float4* __restrict__ gx = gxyzo + (size_t)b * GP;

    extern __shared__ char smem[];
    ull*   s_gkey = (ull*)(smem + OFS_GKEY);
    float* s_gmax = (float*)(smem + OFS_GMAX);
    float* s_cx   = (float*)(smem + OFS_CX);
    float* s_cy   = (float*)(smem + OFS_CY);
    float* s_cz   = (float*)(smem + OFS_CZ);
    float* s_ex   = (float*)(smem + OFS_EX);
    float* s_ey   = (float*)(smem + OFS_EY);
    float* s_ez   = (float*)(smem + OFS_EZ);
    unsigned short* s_list = (unsigned short*)(smem + OFS_LIST);
    ull*   s_part = (ull*)(smem + OFS_PART);
    int*   s_misc = (int*)(smem + OFS_MISC);
    float* s_red  = (float*)(smem + OFS_RED);
    float* s_dist = (float*)(smem + FIXED_BYTES);
    unsigned* s_hist = (unsigned*)s_dist;        // alias, preproc only

    // ---- P1: bbox ----
    float mnx = 1e30f, mny = 1e30f, mnz = 1e30f;
    float mxx = -1e30f, mxy = -1e30f, mxz = -1e30f;
    for (int g = t; g < n; g += THREADS) {
        float x = P[3 * g], y = P[3 * g + 1], z = P[3 * g + 2];
        mnx = fminf(mnx, x); mxx = fmaxf(mxx, x);
        mny = fminf(mny, y); mxy = fmaxf(mxy, y);
        mnz = fminf(mnz, z); mxz = fmaxf(mxz, z);
    }
    mnx = wave_fmin(mnx); mny = wave_fmin(mny); mnz = wave_fmin(mnz);
    mxx = wave_fmax(mxx); mxy = wave_fmax(mxy); mxz = wave_fmax(mxz);
    if (lane == 63) {
        s_red[wid * 6 + 0] = mnx; s_red[wid * 6 + 1] = mny; s_red[wid * 6 + 2] = mnz;
        s_red[wid * 6 + 3] = mxx; s_red[wid * 6 + 4] = mxy; s_red[wid * 6 + 5] = mxz;
    }
    __syncthreads();
    if (t == 0) {
        float a0 = 1e30f, a1 = 1e30f, a2 = 1e30f, b0 = -1e30f, b1 = -1e30f, b2 = -1e30f;
        for (int w = 0; w < NWAVE; ++w) {
            a0 = fminf(a0, s_red[w * 6 + 0]); a1 = fminf(a1, s_red[w * 6 + 1]);
            a2 = fminf(a2, s_red[w * 6 + 2]); b0 = fmaxf(b0, s_red[w * 6 + 3]);
            b1 = fmaxf(b1, s_red[w * 6 + 4]); b2 = fmaxf(b2, s_red[w * 6 + 5]);
        }
        s_red[0] = a0; s_red[1] = a1; s_red[2] = a2;
        s_red[3] = 15.9999f / (b0 - a0 + 1e-20f);
        s_red[4] = 15.9999f / (b1 - a1 + 1e-20f);
        s_red[5] = 15.9999f / (b2 - a2 + 1e-20f);
    }
    __syncthreads();
    const float bx = s_red[0], by = s_red[1], bz = s_red[2];
    const float ivx = s_red[3], ivy = s_red[4], ivz = s_red[5];

    // ---- P2: histogram ----
    for (int i = t; i < 4096; i += THREADS) s_hist[i] = 0;
    __syncthreads();
    for (int g = t; g < n; g += THREADS) {
        float x = P[3 * g], y = P[3 * g + 1], z = P[3 * g + 2];
        atomicAdd(&s_hist[cellof(x, y, z, bx, by, bz, ivx, ivy, ivz)], 1u);
    }
    __syncthreads();

    // ---- P3: exclusive scan over 4096 cells ----
    {
        unsigned c0 = s_hist[4 * t], c1 = s_hist[4 * t + 1];
        unsigned c2 = s_hist[4 * t + 2], c3 = s_hist[4 * t + 3];
        unsigned sum4 = c0 + c1 + c2 + c3;
        unsigned incl = sum4;
        for (int off = 1; off < 64; off <<= 1) {
            unsigned u = (unsigned)__shfl_up((int)incl, off);
            if (lane >= off) incl += u;
        }
        if (lane == 63) s_misc[8 + wid] = (int)incl;
        __syncthreads();
        unsigned woff = 0;
        for (int w = 0; w < wid; ++w) woff += (unsigned)s_misc[8 + w];
        unsigned base = woff + incl - sum4;
        s_hist[4 * t]     = base;
        s_hist[4 * t + 1] = base + c0;
        s_hist[4 * t + 2] = base + c0 + c1;
        s_hist[4 * t + 3] = base + c0 + c1 + c2;
    }
    __syncthreads();

    // ---- P4: scatter (sorted coords + orig idx in .w) ----
    for (int g = t; g < n; g += THREADS) {
        float x = P[3 * g], y = P[3 * g + 1], z = P[3 * g + 2];
        unsigned pos = atomicAdd(&s_hist[cellof(x, y, z, bx, by, bz, ivx, ivy, ivz)], 1u);
        gx[pos] = make_float4(x, y, z, (float)g);
    }
    __syncthreads();

    // ---- P5: per-32-pt-group AABB metadata + init (one group per wave) ----
    for (int g = wid; g < G32; g += NWAVE) {
        int cnt = n - g * 32; if (cnt > 32) cnt = 32;
        bool memb = (lane < 32) && (sub < cnt);
        float4 w = make_float4(0.f, 0.f, 0.f, 0.f);
        if (memb) w = gx[g * 32 + sub];
        float xn = memb ? w.x : 1e30f, xx = memb ? w.x : -1e30f;
        float yn = memb ? w.y : 1e30f, yx = memb ? w.y : -1e30f;
        float zn = memb ? w.z : 1e30f, zx = memb ? w.z : -1e30f;
        xn = __shfl(half_fmin(xn), 31); xx = __shfl(half_fmax(xx), 31);
        yn = __shfl(half_fmin(yn), 31); yx = __shfl(half_fmax(yx), 31);
        zn = __shfl(half_fmin(zn), 31); zx = __shfl(half_fmax(zx), 31);
        if (lane == 0) {
            s_cx[g] = (xn + xx) * 0.5f; s_ex[g] = (xx - xn) * 0.5f + 1e-7f;
            s_cy[g] = (yn + yx) * 0.5f; s_ey[g] = (yx - yn) * 0.5f + 1e-7f;
            s_cz[g] = (zn + zx) * 0.5f; s_ez[g] = (zx - zn) * 0.5f + 1e-7f;
            s_gmax[g] = 1e10f;          // forces iter-1 update of every group
        }
        if (lane < 32) {
            if (!memb) gx[g * 32 + sub] = make_float4(0.f, 0.f, 0.f, 0.f);
            s_dist[g * 32 + sub] = memb ? 1e10f : -1.0f;
        }
    }
    for (int i = t; i < 1024; i += THREADS)
        if (i >= G32) s_gkey[i] = 0;
    if (t == 0) { s_misc[0] = 0; idx_out[(size_t)b * m] = 0; }
    __syncthreads();

    // ---- main loop: A -> bar -> C -> bar -> D1 -> bar -> D2 ----
    float lx = P[0], ly = P[1], lz = P[2];
    const size_t iobase = (size_t)b * m;
    const int DW = (G32 + 63) >> 6;        // waves with real keys in Phase D
    for (int it = 1; it < m; ++it) {
        const int par = (it & 1) * 16;

        // Phase A: AABB prune test (no sqrt), ballot-compacted list
        bool upd = false;
        if (t < G32) {
            float gmax = s_gmax[t];
            float ax = fmaxf(fabsf(lx - s_cx[t]) - s_ex[t], 0.0f);
            float ay = fmaxf(fabsf(ly - s_cy[t]) - s_ey[t], 0.0f);
            float az = fmaxf(fabsf(lz - s_cz[t]) - s_ez[t], 0.0f);
            float lb2 = ax * ax + ay * ay + az * az;
            upd = !(lb2 * 0.9999f - 1e-6f >= gmax);
        }
        {
            ull mask = __ballot(upd);
            if (mask) {
                int cnt = __popcll(mask);
                int base = 0;
                if (lane == 0) base = atomicAdd(&s_misc[0], cnt);
                base = __shfl(base, 0);
                if (upd) {
                    int pw = (int)__popcll(mask & ((1ULL << lane) - 1ULL));
                    s_list[base + pw] = (unsigned short)t;
                }
            }
        }
        __syncthreads();                       // (1)
        const int U = s_misc[0];

        // Phase C: update flagged groups; 2 groups per wave (one per half).
        // r16: no-op skip -- if NO lane's dist decreased, group state (dist,
        // gmax, key) is bit-identical, so skip extraction + writes. ballot
        // is wave-uniform -> the `continue` is uniform (no divergence).
        {
            const int nt = (U + 1) >> 1;
            for (int j0 = wid; j0 < nt; j0 += NWAVE) {
                int e = 2 * j0 + half;
                int g = (e < U) ? (int)s_list[e] : -1;
                int o = g * 32 + sub;
                float4 w = make_float4(0.f, 0.f, 0.f, 0.f);
                float dc = -1.0f;
                if (g >= 0) { w = gx[o]; dc = s_dist[o]; }
                float dx = __fsub_rn(w.x, lx);
                float dy = __fsub_rn(w.y, ly);
                float dz = __fsub_rn(w.z, lz);
                float ds = __fadd_rn(__fadd_rn(__fmul_rn(dx, dx), __fmul_rn(dy, dy)),
                                     __fmul_rn(dz, dz));
                float nd = fminf(dc, ds);
                ull chg = __ballot((g >= 0) && (nd < dc));   // wave-uniform
                if (chg == 0) continue;                      // whole wave no-op
                unsigned hc = half ? (unsigned)(chg >> 32) : (unsigned)chg;
                if ((g >= 0) && (nd < dc)) s_dist[o] = nd;
                // per-half max of nd
                float gmr = nd;
                gmr = fmax_dpp<0x111,0xf>(gmr);
                gmr = fmax_dpp<0x112,0xf>(gmr);
                gmr = fmax_dpp<0x114,0xf>(gmr);
                gmr = fmax_dpp<0x118,0xf>(gmr);
                gmr = fmax_dpp<0x142,0xa>(gmr);
                float gm = __shfl(gmr, lane | 31);         // bcast half max
                ull mask = __ballot(nd == gm);
                unsigned hm = half ? (unsigned)(mask >> 32) : (unsigned)mask;
                int fl = __ffs((int)hm) - 1;               // first matching lane
                int ao = __shfl((int)w.w, (half << 5) + fl);
                bool tie = (hm & (hm - 1u)) != 0u;
                if (__any(tie)) {                           // rare exact ties
                    int morig = (nd == gm) ? (int)w.w : 0x7FFFFFFF;
                    morig = half_imin(morig);
                    int tmin = __shfl(morig, lane | 31);
                    if (tie) ao = tmin;
                }
                if (g >= 0 && sub == 31 && hc != 0u) {     // only changed halves
                    s_gkey[g] = ((ull)__float_as_uint(gm) << 15)
                              | (ull)(unsigned)(0x7fff - ao);
                    s_gmax[g] = gm;
                }
            }
        }
        __syncthreads();                       // (2)

        // Phase D stage 1: per-wave key max (only DW waves have keys)
        ull kk = 0;
        if (wid < DW) kk = wave_kmax(s_gkey[t]);
        if (lane == 63) s_part[par + wid] = kk;
        if (t == 0) s_misc[0] = 0;
        __syncthreads();                       // (3)
        // stage 2: combine 16 partials; decode orig
        ull k2 = s_part[par + (t & 15)];
        k2 = kmax_dpp<0x111,0xf>(k2);
        k2 = kmax_dpp<0x112,0xf>(k2);
        k2 = kmax_dpp<0x114,0xf>(k2);
        k2 = kmax_dpp<0x118,0xf>(k2);          // lane 15 = total
        int lo15 = __builtin_amdgcn_readlane((int)(unsigned)k2, 15);
        int orig = 0x7fff - (lo15 & 0x7fff);
        if (t == 0) idx_out[iobase + it] = orig;
        const float* __restrict__ wp = P + 3 * (size_t)orig;   // uniform scalar load
        lx = wp[0]; ly = wp[1]; lz = wp[2];
    }
}

// Fallback for n > 32767 (not hit for this shape): exact brute force.
__global__ __launch_bounds__(1024)
void fps_brute(const float* __restrict__ C, float* __restrict__ gdist,
               int n, int m, int* __restrict__ idx_out) {
    const int b = blockIdx.x, t = threadIdx.x;
    const int lane = t & 63, wid = t >> 6;
    const float* __restrict__ P = C + (size_t)b * n * 3;
    float* __restrict__ dist = gdist + (size_t)b * n;
    __shared__ ull sp[2][16];
    for (int g = t; g < n; g += 1024) dist[g] = 1e10f;
    if (t == 0) idx_out[(size_t)b * m] = 0;
    float lx = P[0], ly = P[1], lz = P[2];
    __syncthreads();
    for (int it = 1; it < m; ++it) {
        int par = it & 1;
        ull k = 0;
        for (int g = t; g < n; g += 1024) {
            float dx = __fsub_rn(P[3 * g], lx);
            float dy = __fsub_rn(P[3 * g + 1], ly);
            float dz = __fsub_rn(P[3 * g + 2], lz);
            float d = __fadd_rn(__fadd_rn(__fmul_rn(dx, dx), __fmul_rn(dy, dy)),
                                __fmul_rn(dz, dz));
            float nd = fminf(dist[g], d);
            dist[g] = nd;
            ull kk = ((ull)__float_as_uint(nd) << 32) | (unsigned)(~g);
            if (kk > k) k = kk;
        }
        for (int off = 1; off < 64; off <<= 1) {
            ull ok = __shfl_xor(k, off);
            if (ok > k) k = ok;
        }
        if (lane == 0) sp[par][wid] = k;
        __syncthreads();
        ull kmaxv = sp[par][0];
        for (int w = 1; w < 16; ++w) { ull v = sp[par][w]; if (v > kmaxv) kmaxv = v; }
        int sbi = (int)~(unsigned)kmaxv;
        if (t == 0) idx_out[(size_t)b * m + it] = sbi;
        const float* wp = P + 3 * (size_t)(unsigned)sbi;
        lx = wp[0]; ly = wp[1]; lz = wp[2];
    }
}

__global__ void gather_kernel(const float* __restrict__ C,
                              const float* __restrict__ F,
                              const int* __restrict__ idx,
                              float* __restrict__ outC,
                              float* __restrict__ outF,
                              int n_pts, int m, int c) {
    int pair = blockIdx.x;            // b*m + s
    int b = pair / m;
    int src = idx[pair];
    size_t srcbase = (size_t)b * n_pts + src;
    const float* sF = F + srcbase * (size_t)c;
    float* dF = outF + (size_t)pair * c;
    for (int i = threadIdx.x; i < c; i += blockDim.x) dF[i] = sF[i];
    if (threadIdx.x < 3)
        outC[(size_t)pair * 3 + threadIdx.x] = C[srcbase * 3 + threadIdx.x];
}

extern "C" void kernel_launch(void* const* d_in, const int* in_sizes, int n_in,
                              void* d_out, int out_size, void* d_ws, size_t ws_size,
                              hipStream_t stream) {
    const float* C = (const float*)d_in[0];
    const float* F = (const float*)d_in[1];

    int n_total = in_sizes[0] / 3;
    int c       = in_sizes[1] / n_total;
    int bm      = out_size / (3 + c);

    int batch = 8;
    if (bm % 2000 == 0) {
        int bb = bm / 2000;
        if (bb > 0 && n_total % bb == 0 && n_total / bb >= 2000) batch = bb;
    }
    int n_pts = n_total / batch;
    int m     = (n_pts < 2000) ? n_pts : 2000;

    int* idxbuf = (int*)d_ws;
    float* outC = (float*)d_out;
    float* outF = outC + (size_t)batch * m * 3;

    int G32 = (n_pts + 31) >> 5;
    int GP  = G32 << 5;
    size_t idxbytes = (((size_t)batch * m * 4) + 255) & ~(size_t)255;
    size_t scrbytes = (size_t)batch * GP * 16;
    void* scratch;
    if (ws_size >= idxbytes + scrbytes)
        scratch = (char*)d_ws + idxbytes;
    else
        scratch = (char*)d_out + ((((size_t)out_size * 4) - scrbytes) & ~(size_t)15);

    if (n_pts <= 32767) {
        int distbytes = GP * 4; if (distbytes < 16384) distbytes = 16384;
        size_t smem = (size_t)FIXED_BYTES + distbytes;
        hipFuncSetAttribute((const void*)fps_grouped,
                            hipFuncAttributeMaxDynamicSharedMemorySize, (int)smem);
        fps_grouped<<<batch, THREADS, smem, stream>>>(C, (float4*)scratch,
                                                      n_pts, m, G32, idxbuf);
    } else {
        fps_brute<<<batch, 1024, 0, stream>>>(C, (float*)scratch, n_pts, m, idxbuf);
    }

    gather_kernel<<<batch * m, 128, 0, stream>>>(C, F, idxbuf, outC, outF,
                                                 n_pts, m, c);
}